// Round 1
// baseline (170.698 us; speedup 1.0000x reference)
//
#include <hip/hip_runtime.h>

#define SEQ   2048
#define DMODEL 512
#define NHEAD 8
#define DKH   64
#define WIN   64
#define NEGV  -1000000000.0f

// ---------------------------------------------------------------------------
// NT GEMM: P[m,n] = sum_k X[m,k] * Wt[n,k] (+ bias[n])
// M=2048 (grid.x*64), N=512 (grid.y*64), K=512. 256 threads, 4x4 microtile.
// ---------------------------------------------------------------------------
template<bool BIAS>
__device__ __forceinline__ void gemm_nt_body(const float* __restrict__ X,
                                             const float* __restrict__ Wt,
                                             const float* __restrict__ bias,
                                             float* __restrict__ P)
{
    __shared__ float As[16][68];   // [k][m], stride 68 floats = 272B (16B aligned)
    __shared__ float Bs[16][68];   // [k][n]
    const int tid = threadIdx.x;
    const int m0 = blockIdx.x * 64;
    const int n0 = blockIdx.y * 64;
    const int tx = tid & 15;
    const int ty = tid >> 4;
    const int lr = tid >> 2;          // 0..63 (row in tile)
    const int kc = (tid & 3) * 4;     // 0,4,8,12 (k sub-col)

    float acc[4][4] = {};

    for (int k0 = 0; k0 < 512; k0 += 16) {
        float4 a = *(const float4*)&X [(m0 + lr) * DMODEL + k0 + kc];
        float4 b = *(const float4*)&Wt[(n0 + lr) * DMODEL + k0 + kc];
        As[kc + 0][lr] = a.x; As[kc + 1][lr] = a.y;
        As[kc + 2][lr] = a.z; As[kc + 3][lr] = a.w;
        Bs[kc + 0][lr] = b.x; Bs[kc + 1][lr] = b.y;
        Bs[kc + 2][lr] = b.z; Bs[kc + 3][lr] = b.w;
        __syncthreads();
        #pragma unroll
        for (int kk = 0; kk < 16; kk++) {
            float4 av = *(const float4*)&As[kk][ty * 4];
            float4 bv = *(const float4*)&Bs[kk][tx * 4];
            float aa[4] = {av.x, av.y, av.z, av.w};
            float bb[4] = {bv.x, bv.y, bv.z, bv.w};
            #pragma unroll
            for (int i = 0; i < 4; i++)
                #pragma unroll
                for (int j = 0; j < 4; j++)
                    acc[i][j] += aa[i] * bb[j];
        }
        __syncthreads();
    }

    float4 bo4 = make_float4(0.f, 0.f, 0.f, 0.f);
    if (BIAS) bo4 = *(const float4*)&bias[n0 + tx * 4];
    #pragma unroll
    for (int i = 0; i < 4; i++) {
        float4 o;
        o.x = acc[i][0] + bo4.x;
        o.y = acc[i][1] + bo4.y;
        o.z = acc[i][2] + bo4.z;
        o.w = acc[i][3] + bo4.w;
        *(float4*)&P[(m0 + ty * 4 + i) * DMODEL + n0 + tx * 4] = o;
    }
}

__global__ __launch_bounds__(256)
void qkv_proj_kernel(const float* __restrict__ q, const float* __restrict__ k,
                     const float* __restrict__ v,
                     const float* __restrict__ Wq, const float* __restrict__ Wk,
                     const float* __restrict__ Wv,
                     float* __restrict__ Qo, float* __restrict__ Ko,
                     float* __restrict__ Vo)
{
    const float* X; const float* Wm; float* P;
    if (blockIdx.z == 0)      { X = q; Wm = Wq; P = Qo; }
    else if (blockIdx.z == 1) { X = k; Wm = Wk; P = Ko; }
    else                      { X = v; Wm = Wv; P = Vo; }
    gemm_nt_body<false>(X, Wm, nullptr, P);
}

__global__ __launch_bounds__(256)
void out_proj_kernel(const float* __restrict__ ctx, const float* __restrict__ Wo,
                     const float* __restrict__ bo, float* __restrict__ out)
{
    gemm_nt_body<true>(ctx, Wo, bo, out);
}

// ---------------------------------------------------------------------------
// Windowed attention: block = (16 queries, 1 head). 256 threads.
// Scores over r=0..64 (key = i-64+r), decay bias, softmax, PV, attn_w.
// ---------------------------------------------------------------------------
__global__ __launch_bounds__(256)
void attn_kernel(const float* __restrict__ Q, const float* __restrict__ K,
                 const float* __restrict__ V, float* __restrict__ ctx,
                 float* __restrict__ attnw)
{
    __shared__ float Qs[16][68];
    __shared__ float Ks[80][68];
    __shared__ float Vs[80][68];
    __shared__ float Ps[16][66];

    const int h   = blockIdx.y;
    const int q0  = blockIdx.x * 16;
    const int tid = threadIdx.x;

    // stage Q (16 rows x 64)
    {
        int row = tid >> 4, c4 = (tid & 15) * 4;
        *(float4*)&Qs[row][c4] =
            *(const float4*)&Q[(q0 + row) * DMODEL + h * DKH + c4];
    }
    // stage K/V window rows q0-64 .. q0+15  (80 rows x 64)
    for (int li = tid; li < 80 * 16; li += 256) {
        int row = li >> 4, c4 = (li & 15) * 4;
        int g = q0 - 64 + row;
        float4 kv = make_float4(0.f, 0.f, 0.f, 0.f);
        float4 vv = make_float4(0.f, 0.f, 0.f, 0.f);
        if (g >= 0) {
            kv = *(const float4*)&K[g * DMODEL + h * DKH + c4];
            vv = *(const float4*)&V[g * DMODEL + h * DKH + c4];
        }
        *(float4*)&Ks[row][c4] = kv;
        *(float4*)&Vs[row][c4] = vv;
    }
    __syncthreads();

    // scores: 16 q x 65 r
    for (int t = tid; t < 16 * 65; t += 256) {
        int q = t / 65, r = t % 65;
        int g = q0 + q - 64 + r;
        float s = 0.f;
        #pragma unroll
        for (int x = 0; x < 64; x += 4) {
            float4 qa = *(const float4*)&Qs[q][x];
            float4 ka = *(const float4*)&Ks[q + r][x];
            s += qa.x * ka.x + qa.y * ka.y + qa.z * ka.z + qa.w * ka.w;
        }
        float sc;
        if (g >= 0)
            sc = s * 0.125f + 0.1f * __expf(-0.1f * (float)(64 - r));
        else
            sc = NEGV;
        Ps[q][r] = sc;
    }
    __syncthreads();

    // softmax per row (65 entries): one wave per row, lane<64 + scalar tail
    {
        int wave = tid >> 6;
        int lane = tid & 63;
        for (int q = wave; q < 16; q += 4) {
            float v    = Ps[q][lane];
            float v64  = Ps[q][64];
            float m = v;
            #pragma unroll
            for (int off = 32; off >= 1; off >>= 1)
                m = fmaxf(m, __shfl_xor(m, off));
            m = fmaxf(m, v64);
            float e   = __expf(v - m);
            float e64 = __expf(v64 - m);
            float ssum = e;
            #pragma unroll
            for (int off = 32; off >= 1; off >>= 1)
                ssum += __shfl_xor(ssum, off);
            ssum += e64;
            float inv = 1.f / ssum;
            Ps[q][lane] = e * inv;
            if (lane == 0) Ps[q][64] = e64 * inv;
        }
    }
    __syncthreads();

    // PV: thread -> (q, dk4)
    {
        int q  = tid >> 4;
        int c4 = (tid & 15) * 4;
        float4 o = make_float4(0.f, 0.f, 0.f, 0.f);
        for (int r = 0; r <= 64; r++) {
            float p = Ps[q][r];
            float4 vv = *(const float4*)&Vs[q + r][c4];
            o.x += p * vv.x; o.y += p * vv.y;
            o.z += p * vv.z; o.w += p * vv.w;
        }
        *(float4*)&ctx[(q0 + q) * DMODEL + h * DKH + c4] = o;
    }

    // attn_w: 16 rows x 128 slots, zeros where not stored
    for (int t = tid; t < 16 * 128; t += 256) {
        int q = t >> 7, slot = t & 127;
        int i = q0 + q;
        float val = 0.f;
        if (i < WIN) {
            if (slot <= i) val = Ps[q][slot + WIN - i];
        } else if (i >= SEQ - WIN) {
            if (slot <= WIN) val = Ps[q][slot];
        }
        attnw[(h * SEQ + i) * 2 * WIN + slot] = val;
    }
}

// ---------------------------------------------------------------------------
extern "C" void kernel_launch(void* const* d_in, const int* in_sizes, int n_in,
                              void* d_out, int out_size, void* d_ws, size_t ws_size,
                              hipStream_t stream)
{
    const float* query = (const float*)d_in[0];
    const float* key   = (const float*)d_in[1];
    const float* value = (const float*)d_in[2];
    const float* Wq    = (const float*)d_in[3];
    const float* Wk    = (const float*)d_in[4];
    const float* Wv    = (const float*)d_in[5];
    const float* Wo    = (const float*)d_in[6];
    const float* bo    = (const float*)d_in[7];

    float* out   = (float*)d_out;                 // 2048*512
    float* attnw = out + SEQ * DMODEL;            // 8*2048*128

    float* Qw = (float*)d_ws;
    float* Kw = Qw + SEQ * DMODEL;
    float* Vw = Kw + SEQ * DMODEL;
    float* Cw = Vw + SEQ * DMODEL;

    dim3 g1(SEQ / 64, DMODEL / 64, 3);
    qkv_proj_kernel<<<g1, 256, 0, stream>>>(query, key, value, Wq, Wk, Wv,
                                            Qw, Kw, Vw);

    dim3 g2(SEQ / 16, NHEAD);
    attn_kernel<<<g2, 256, 0, stream>>>(Qw, Kw, Vw, Cw, attnw);

    dim3 g3(SEQ / 64, DMODEL / 64);
    out_proj_kernel<<<g3, 256, 0, stream>>>(Cw, Wo, bo, out);
}

// Round 2
// 127.363 us; speedup vs baseline: 1.3403x; 1.3403x over previous
//
#include <hip/hip_runtime.h>
#include <stdint.h>

#define SEQ   2048
#define DM    512
#define NHEAD 8
#define DKH   64
#define WIN   64
#define NEGV  -1000000000.0f

typedef __attribute__((ext_vector_type(8))) short   short8;
typedef __attribute__((ext_vector_type(4))) float   float4v;
typedef __attribute__((ext_vector_type(8))) unsigned short ushort8v;

__device__ __forceinline__ unsigned short f2bf(float x) {
    uint32_t u = __float_as_uint(x);
    uint32_t r = (u + 0x7FFFu + ((u >> 16) & 1u)) >> 16;
    return (unsigned short)r;
}

// async 16B global -> LDS (wave-uniform base + lane*16 pattern)
__device__ __forceinline__ void async_cp16(const void* g, void* lds) {
    __builtin_amdgcn_global_load_lds(
        (const __attribute__((address_space(1))) unsigned int*)(uintptr_t)g,
        (__attribute__((address_space(3))) unsigned int*)(uint32_t)(uintptr_t)lds,
        16, 0, 0);
}

// ---------------------------------------------------------------------------
// Fused f32 -> bf16 cast of q,k,v (1M each) + Wq,Wk,Wv,Wo (256K each).
// dst is the concatenation in that order. 8 elems / thread.
// ---------------------------------------------------------------------------
__global__ __launch_bounds__(256)
void cast7_kernel(const float* __restrict__ q, const float* __restrict__ k,
                  const float* __restrict__ v, const float* __restrict__ wq,
                  const float* __restrict__ wk, const float* __restrict__ wv,
                  const float* __restrict__ wo, unsigned short* __restrict__ dst)
{
    int g = (blockIdx.x * 256 + threadIdx.x) * 8;   // < 4194304
    const float* src; int off;
    if      (g < 1048576) { src = q;  off = g; }
    else if (g < 2097152) { src = k;  off = g - 1048576; }
    else if (g < 3145728) { src = v;  off = g - 2097152; }
    else if (g < 3407872) { src = wq; off = g - 3145728; }
    else if (g < 3670016) { src = wk; off = g - 3407872; }
    else if (g < 3932160) { src = wv; off = g - 3670016; }
    else                  { src = wo; off = g - 3932160; }
    float4 x0 = *(const float4*)(src + off);
    float4 x1 = *(const float4*)(src + off + 4);
    ushort8v o;
    o[0] = f2bf(x0.x); o[1] = f2bf(x0.y); o[2] = f2bf(x0.z); o[3] = f2bf(x0.w);
    o[4] = f2bf(x1.x); o[5] = f2bf(x1.y); o[6] = f2bf(x1.z); o[7] = f2bf(x1.w);
    *(ushort8v*)(dst + g) = o;
}

// ---------------------------------------------------------------------------
// bf16 MFMA NT GEMM: C[m,n] = sum_k A[m,k]*B[n,k] (+bias[n]), f32 out.
// K=512, ldc=512. 128x128 tile / block, 256 threads = 4 waves (2x2 of 64x64).
// LDS tiles 128x32 bf16 k-major (64B rows, no pad -> global_load_lds ok).
// ---------------------------------------------------------------------------
template<bool BIAS>
__device__ __forceinline__ void gemm_mfma_body(const unsigned short* __restrict__ A,
                                               const unsigned short* __restrict__ B,
                                               const float* __restrict__ bias,
                                               float* __restrict__ C)
{
    __shared__ __align__(16) unsigned short As[128 * 32];
    __shared__ __align__(16) unsigned short Bs[128 * 32];

    const int tid  = threadIdx.x;
    const int m0   = blockIdx.x * 128;
    const int n0   = blockIdx.y * 128;
    const int lane = tid & 63;
    const int wave = tid >> 6;
    const int wm   = (wave >> 1) * 64;
    const int wn   = (wave & 1) * 64;
    const int lm   = lane & 15;
    const int lk   = (lane >> 4) * 8;     // k-subchunk (elements)

    float4v acc[4][4] = {};

    for (int k0 = 0; k0 < 512; k0 += 32) {
        #pragma unroll
        for (int h = 0; h < 2; h++) {
            int c  = tid + h * 256;       // chunk 0..511
            int r  = c >> 2;              // tile row 0..127
            int kc = (c & 3) * 8;         // k elems 0/8/16/24
            async_cp16(A + (size_t)(m0 + r) * 512 + k0 + kc, As + c * 8);
            async_cp16(B + (size_t)(n0 + r) * 512 + k0 + kc, Bs + c * 8);
        }
        __syncthreads();

        short8 av[4], bv[4];
        #pragma unroll
        for (int mt = 0; mt < 4; mt++)
            av[mt] = *(const short8*)(As + (wm + mt * 16 + lm) * 32 + lk);
        #pragma unroll
        for (int nt = 0; nt < 4; nt++)
            bv[nt] = *(const short8*)(Bs + (wn + nt * 16 + lm) * 32 + lk);
        #pragma unroll
        for (int mt = 0; mt < 4; mt++)
            #pragma unroll
            for (int nt = 0; nt < 4; nt++)
                acc[mt][nt] = __builtin_amdgcn_mfma_f32_16x16x32_bf16(
                    av[mt], bv[nt], acc[mt][nt], 0, 0, 0);
        __syncthreads();
    }

    const int r0 = (lane >> 4) * 4;
    const int cn = lane & 15;
    #pragma unroll
    for (int nt = 0; nt < 4; nt++) {
        int gcol = n0 + wn + nt * 16 + cn;
        float b = BIAS ? bias[gcol] : 0.f;
        #pragma unroll
        for (int mt = 0; mt < 4; mt++) {
            int grow = m0 + wm + mt * 16 + r0;
            #pragma unroll
            for (int reg = 0; reg < 4; reg++)
                C[(size_t)(grow + reg) * 512 + gcol] = acc[mt][nt][reg] + b;
        }
    }
}

__global__ __launch_bounds__(256)
void qkv_gemm_kernel(const unsigned short* __restrict__ qb,
                     const unsigned short* __restrict__ kb,
                     const unsigned short* __restrict__ vb,
                     const unsigned short* __restrict__ wqb,
                     const unsigned short* __restrict__ wkb,
                     const unsigned short* __restrict__ wvb,
                     float* __restrict__ Qf, float* __restrict__ Kf,
                     float* __restrict__ Vf)
{
    const unsigned short *A, *B; float* C;
    if (blockIdx.z == 0)      { A = qb; B = wqb; C = Qf; }
    else if (blockIdx.z == 1) { A = kb; B = wkb; C = Kf; }
    else                      { A = vb; B = wvb; C = Vf; }
    gemm_mfma_body<false>(A, B, nullptr, C);
}

__global__ __launch_bounds__(256)
void out_gemm_kernel(const unsigned short* __restrict__ ctxb,
                     const unsigned short* __restrict__ wob,
                     const float* __restrict__ bo, float* __restrict__ out)
{
    gemm_mfma_body<true>(ctxb, wob, bo, out);
}

// ---------------------------------------------------------------------------
// Windowed attention: block = (16 queries, 1 head). 256 threads.
// Reads f32 Q/K/V, writes attn_w (f32) and ctx in bf16.
// ---------------------------------------------------------------------------
__global__ __launch_bounds__(256)
void attn_kernel(const float* __restrict__ Q, const float* __restrict__ K,
                 const float* __restrict__ V, unsigned short* __restrict__ ctxb,
                 float* __restrict__ attnw)
{
    __shared__ float Qs[16][68];
    __shared__ float Ks[80][68];
    __shared__ float Vs[80][68];
    __shared__ float Ps[16][66];

    const int h   = blockIdx.y;
    const int q0  = blockIdx.x * 16;
    const int tid = threadIdx.x;

    {
        int row = tid >> 4, c4 = (tid & 15) * 4;
        *(float4*)&Qs[row][c4] =
            *(const float4*)&Q[(q0 + row) * DM + h * DKH + c4];
    }
    for (int li = tid; li < 80 * 16; li += 256) {
        int row = li >> 4, c4 = (li & 15) * 4;
        int g = q0 - 64 + row;
        float4 kv = make_float4(0.f, 0.f, 0.f, 0.f);
        float4 vv = make_float4(0.f, 0.f, 0.f, 0.f);
        if (g >= 0) {
            kv = *(const float4*)&K[g * DM + h * DKH + c4];
            vv = *(const float4*)&V[g * DM + h * DKH + c4];
        }
        *(float4*)&Ks[row][c4] = kv;
        *(float4*)&Vs[row][c4] = vv;
    }
    __syncthreads();

    for (int t = tid; t < 16 * 65; t += 256) {
        int q = t / 65, r = t % 65;
        int g = q0 + q - 64 + r;
        float s = 0.f;
        #pragma unroll
        for (int x = 0; x < 64; x += 4) {
            float4 qa = *(const float4*)&Qs[q][x];
            float4 ka = *(const float4*)&Ks[q + r][x];
            s += qa.x * ka.x + qa.y * ka.y + qa.z * ka.z + qa.w * ka.w;
        }
        Ps[q][r] = (g >= 0)
            ? s * 0.125f + 0.1f * __expf(-0.1f * (float)(64 - r))
            : NEGV;
    }
    __syncthreads();

    {
        int wave = tid >> 6;
        int lane = tid & 63;
        for (int q = wave; q < 16; q += 4) {
            float v    = Ps[q][lane];
            float v64  = Ps[q][64];
            float m = v;
            #pragma unroll
            for (int off = 32; off >= 1; off >>= 1)
                m = fmaxf(m, __shfl_xor(m, off));
            m = fmaxf(m, v64);
            float e   = __expf(v - m);
            float e64 = __expf(v64 - m);
            float ssum = e;
            #pragma unroll
            for (int off = 32; off >= 1; off >>= 1)
                ssum += __shfl_xor(ssum, off);
            ssum += e64;
            float inv = 1.f / ssum;
            Ps[q][lane] = e * inv;
            if (lane == 0) Ps[q][64] = e64 * inv;
        }
    }
    __syncthreads();

    {
        int q  = tid >> 4;
        int c4 = (tid & 15) * 4;
        float4 o = make_float4(0.f, 0.f, 0.f, 0.f);
        for (int r = 0; r <= 64; r++) {
            float p = Ps[q][r];
            float4 vv = *(const float4*)&Vs[q + r][c4];
            o.x += p * vv.x; o.y += p * vv.y;
            o.z += p * vv.z; o.w += p * vv.w;
        }
        ushort4 o4 = make_ushort4(f2bf(o.x), f2bf(o.y), f2bf(o.z), f2bf(o.w));
        *(ushort4*)&ctxb[(q0 + q) * DM + h * DKH + c4] = o4;
    }

    for (int t = tid; t < 16 * 128; t += 256) {
        int q = t >> 7, slot = t & 127;
        int i = q0 + q;
        float val = 0.f;
        if (i < WIN) {
            if (slot <= i) val = Ps[q][slot + WIN - i];
        } else if (i >= SEQ - WIN) {
            if (slot <= WIN) val = Ps[q][slot];
        }
        attnw[(h * SEQ + i) * 2 * WIN + slot] = val;
    }
}

// ---------------------------------------------------------------------------
extern "C" void kernel_launch(void* const* d_in, const int* in_sizes, int n_in,
                              void* d_out, int out_size, void* d_ws, size_t ws_size,
                              hipStream_t stream)
{
    const float* query = (const float*)d_in[0];
    const float* key   = (const float*)d_in[1];
    const float* value = (const float*)d_in[2];
    const float* Wq    = (const float*)d_in[3];
    const float* Wk    = (const float*)d_in[4];
    const float* Wv    = (const float*)d_in[5];
    const float* Wo    = (const float*)d_in[6];
    const float* bo    = (const float*)d_in[7];

    float* out   = (float*)d_out;                 // 2048*512 f32
    float* attnw = out + SEQ * DM;                // 8*2048*128 f32

    // ws layout: bf16 region then f32 region
    unsigned short* qb   = (unsigned short*)d_ws;       // 1M
    unsigned short* kb   = qb  + 1048576;               // 1M
    unsigned short* vb   = kb  + 1048576;               // 1M
    unsigned short* wqb  = vb  + 1048576;               // 256K
    unsigned short* wkb  = wqb + 262144;
    unsigned short* wvb  = wkb + 262144;
    unsigned short* wob  = wvb + 262144;
    unsigned short* ctxb = wob + 262144;                // 1M
    float* Qf = (float*)(ctxb + 1048576);               // 1M f32
    float* Kf = Qf + 1048576;
    float* Vf = Kf + 1048576;

    cast7_kernel<<<2048, 256, 0, stream>>>(query, key, value, Wq, Wk, Wv, Wo, qb);

    dim3 g1(SEQ / 128, DM / 128, 3);
    qkv_gemm_kernel<<<g1, 256, 0, stream>>>(qb, kb, vb, wqb, wkb, wvb, Qf, Kf, Vf);

    dim3 g2(SEQ / 16, NHEAD);
    attn_kernel<<<g2, 256, 0, stream>>>(Qf, Kf, Vf, ctxb, attnw);

    dim3 g3(SEQ / 128, DM / 128);
    out_gemm_kernel<<<g3, 256, 0, stream>>>(ctxb, wob, bo, out);
}

// Round 3
// 113.762 us; speedup vs baseline: 1.5005x; 1.1196x over previous
//
#include <hip/hip_runtime.h>
#include <stdint.h>

#define SEQ   2048
#define DM    512
#define NHEAD 8
#define DKH   64
#define WIN   64
#define NEGV  -1000000000.0f

typedef __attribute__((ext_vector_type(8))) short          short8;
typedef __attribute__((ext_vector_type(4))) float          float4v;
typedef __attribute__((ext_vector_type(8))) unsigned short ushort8v;

__device__ __forceinline__ unsigned short f2bf(float x) {
    uint32_t u = __float_as_uint(x);
    uint32_t r = (u + 0x7FFFu + ((u >> 16) & 1u)) >> 16;
    return (unsigned short)r;
}
__device__ __forceinline__ float bf2f(unsigned short u) {
    return __uint_as_float(((uint32_t)u) << 16);
}

// async 16B global -> LDS (wave-uniform base + lane*16 pattern)
__device__ __forceinline__ void async_cp16(const void* g, void* lds) {
    __builtin_amdgcn_global_load_lds(
        (const __attribute__((address_space(1))) unsigned int*)(uintptr_t)g,
        (__attribute__((address_space(3))) unsigned int*)(uint32_t)(uintptr_t)lds,
        16, 0, 0);
}

// ---------------------------------------------------------------------------
// Fused f32 -> bf16 cast of q,k,v (1M each) + Wq,Wk,Wv,Wo (256K each).
// ---------------------------------------------------------------------------
__global__ __launch_bounds__(256)
void cast7_kernel(const float* __restrict__ q, const float* __restrict__ k,
                  const float* __restrict__ v, const float* __restrict__ wq,
                  const float* __restrict__ wk, const float* __restrict__ wv,
                  const float* __restrict__ wo, unsigned short* __restrict__ dst)
{
    int g = (blockIdx.x * 256 + threadIdx.x) * 8;   // < 4194304
    const float* src; int off;
    if      (g < 1048576) { src = q;  off = g; }
    else if (g < 2097152) { src = k;  off = g - 1048576; }
    else if (g < 3145728) { src = v;  off = g - 2097152; }
    else if (g < 3407872) { src = wq; off = g - 3145728; }
    else if (g < 3670016) { src = wk; off = g - 3407872; }
    else if (g < 3932160) { src = wv; off = g - 3670016; }
    else                  { src = wo; off = g - 3932160; }
    float4 x0 = *(const float4*)(src + off);
    float4 x1 = *(const float4*)(src + off + 4);
    ushort8v o;
    o[0] = f2bf(x0.x); o[1] = f2bf(x0.y); o[2] = f2bf(x0.z); o[3] = f2bf(x0.w);
    o[4] = f2bf(x1.x); o[5] = f2bf(x1.y); o[6] = f2bf(x1.z); o[7] = f2bf(x1.w);
    *(ushort8v*)(dst + g) = o;
}

// ---------------------------------------------------------------------------
// bf16 MFMA NT GEMM: C[m,n] = sum_k A[m,k]*B[n,k] (+bias[n]).
// OUT_BF16 selects bf16 or f32 output. 128x128 tile, 256 thr = 4 waves.
// ---------------------------------------------------------------------------
template<bool BIAS, bool OUT_BF16>
__device__ __forceinline__ void gemm_mfma_body(const unsigned short* __restrict__ A,
                                               const unsigned short* __restrict__ B,
                                               const float* __restrict__ bias,
                                               void* __restrict__ Cv)
{
    __shared__ __align__(16) unsigned short As[128 * 32];
    __shared__ __align__(16) unsigned short Bs[128 * 32];

    const int tid  = threadIdx.x;
    const int m0   = blockIdx.x * 128;
    const int n0   = blockIdx.y * 128;
    const int lane = tid & 63;
    const int wave = tid >> 6;
    const int wm   = (wave >> 1) * 64;
    const int wn   = (wave & 1) * 64;
    const int lm   = lane & 15;
    const int lk   = (lane >> 4) * 8;

    float4v acc[4][4] = {};

    for (int k0 = 0; k0 < 512; k0 += 32) {
        #pragma unroll
        for (int h = 0; h < 2; h++) {
            int c  = tid + h * 256;
            int r  = c >> 2;
            int kc = (c & 3) * 8;
            async_cp16(A + (size_t)(m0 + r) * 512 + k0 + kc, As + c * 8);
            async_cp16(B + (size_t)(n0 + r) * 512 + k0 + kc, Bs + c * 8);
        }
        __syncthreads();

        short8 av[4], bv[4];
        #pragma unroll
        for (int mt = 0; mt < 4; mt++)
            av[mt] = *(const short8*)(As + (wm + mt * 16 + lm) * 32 + lk);
        #pragma unroll
        for (int nt = 0; nt < 4; nt++)
            bv[nt] = *(const short8*)(Bs + (wn + nt * 16 + lm) * 32 + lk);
        #pragma unroll
        for (int mt = 0; mt < 4; mt++)
            #pragma unroll
            for (int nt = 0; nt < 4; nt++)
                acc[mt][nt] = __builtin_amdgcn_mfma_f32_16x16x32_bf16(
                    av[mt], bv[nt], acc[mt][nt], 0, 0, 0);
        __syncthreads();
    }

    const int r0 = (lane >> 4) * 4;
    const int cn = lane & 15;
    #pragma unroll
    for (int nt = 0; nt < 4; nt++) {
        int gcol = n0 + wn + nt * 16 + cn;
        float b = BIAS ? bias[gcol] : 0.f;
        #pragma unroll
        for (int mt = 0; mt < 4; mt++) {
            int grow = m0 + wm + mt * 16 + r0;
            #pragma unroll
            for (int reg = 0; reg < 4; reg++) {
                float val = acc[mt][nt][reg] + b;
                if (OUT_BF16)
                    ((unsigned short*)Cv)[(size_t)(grow + reg) * 512 + gcol] = f2bf(val);
                else
                    ((float*)Cv)[(size_t)(grow + reg) * 512 + gcol] = val;
            }
        }
    }
}

__global__ __launch_bounds__(256)
void qkv_gemm_kernel(const unsigned short* __restrict__ qb,
                     const unsigned short* __restrict__ kb,
                     const unsigned short* __restrict__ vb,
                     const unsigned short* __restrict__ wqb,
                     const unsigned short* __restrict__ wkb,
                     const unsigned short* __restrict__ wvb,
                     unsigned short* __restrict__ Qp, unsigned short* __restrict__ Kp,
                     unsigned short* __restrict__ Vp)
{
    const unsigned short *A, *B; unsigned short* C;
    if (blockIdx.z == 0)      { A = qb; B = wqb; C = Qp; }
    else if (blockIdx.z == 1) { A = kb; B = wkb; C = Kp; }
    else                      { A = vb; B = wvb; C = Vp; }
    gemm_mfma_body<false, true>(A, B, nullptr, C);
}

__global__ __launch_bounds__(256)
void out_gemm_kernel(const unsigned short* __restrict__ ctxb,
                     const unsigned short* __restrict__ wob,
                     const float* __restrict__ bo, float* __restrict__ out)
{
    gemm_mfma_body<true, false>(ctxb, wob, bo, out);
}

// ---------------------------------------------------------------------------
// MFMA windowed attention. Block = 64 queries x 1 head, 256 thr = 4 waves.
// Wave w owns queries q0+w*16..+15 and key rows (local) w*16..w*16+79.
// LDS rows padded (72 / 136 ushorts) to keep b128 reads at the 8-phase floor.
// ---------------------------------------------------------------------------
__global__ __launch_bounds__(256)
void attn_kernel(const unsigned short* __restrict__ Qp,
                 const unsigned short* __restrict__ Kp,
                 const unsigned short* __restrict__ Vp,
                 unsigned short* __restrict__ ctxb,
                 float* __restrict__ attnw)
{
    __shared__ __align__(16) unsigned short Qs[64 * 72];    // [q_local][64 k]
    __shared__ __align__(16) unsigned short Ks[128 * 72];   // [key_local][64 k]
    __shared__ __align__(16) unsigned short Vt[64 * 136];   // [d][key_local]
    __shared__ __align__(16) unsigned short Ps[4][16][96];  // [wave][q][kk]

    const int h   = blockIdx.y;
    const int q0  = blockIdx.x * 64;
    const int tid = threadIdx.x;

    // ---- stage Q: 64 rows x 8 chunks of 16B
    for (int c = tid; c < 512; c += 256) {
        int row = c >> 3, ch = c & 7;
        *(ushort8v*)&Qs[row * 72 + ch * 8] =
            *(const ushort8v*)&Qp[(size_t)(q0 + row) * 512 + h * 64 + ch * 8];
    }
    // ---- stage K: 128 rows (g = q0-64+row), zero-fill g<0
    for (int c = tid; c < 1024; c += 256) {
        int row = c >> 3, ch = c & 7;
        int g = q0 - 64 + row;
        ushort8v val = {0, 0, 0, 0, 0, 0, 0, 0};
        if (g >= 0)
            val = *(const ushort8v*)&Kp[(size_t)g * 512 + h * 64 + ch * 8];
        *(ushort8v*)&Ks[row * 72 + ch * 8] = val;
    }
    // ---- stage V transposed: Vt[d][key]
    {
        int key = tid >> 1, dh = tid & 1;
        int g = q0 - 64 + key;
        ushort8v vv[4];
        #pragma unroll
        for (int j = 0; j < 4; j++) {
            ushort8v z = {0, 0, 0, 0, 0, 0, 0, 0};
            vv[j] = (g >= 0)
                ? *(const ushort8v*)&Vp[(size_t)g * 512 + h * 64 + dh * 32 + j * 8]
                : z;
        }
        #pragma unroll
        for (int j = 0; j < 4; j++)
            #pragma unroll
            for (int e = 0; e < 8; e++)
                Vt[(dh * 32 + j * 8 + e) * 136 + key] = vv[j][e];
    }
    __syncthreads();

    const int lane = tid & 63;
    const int w    = tid >> 6;
    const int lm   = lane & 15;        // C-layout col / frag m index
    const int g16  = lane >> 4;
    const int lk8  = g16 * 8;

    // ---- QK^T: 5 key tiles x (2 MFMA, K=64)
    short8 av0 = *(const short8*)&Qs[(w * 16 + lm) * 72 + lk8];
    short8 av1 = *(const short8*)&Qs[(w * 16 + lm) * 72 + 32 + lk8];
    float4v sc[5];
    #pragma unroll
    for (int kt = 0; kt < 5; kt++) {
        const unsigned short* kr = &Ks[(w * 16 + kt * 16 + lm) * 72];
        short8 b0 = *(const short8*)(kr + lk8);
        short8 b1 = *(const short8*)(kr + 32 + lk8);
        float4v a = {0.f, 0.f, 0.f, 0.f};
        a = __builtin_amdgcn_mfma_f32_16x16x32_bf16(av0, b0, a, 0, 0, 0);
        a = __builtin_amdgcn_mfma_f32_16x16x32_bf16(av1, b1, a, 0, 0, 0);
        sc[kt] = a;
    }

    // ---- bias + mask (C layout: col=lm is key, row=g16*4+reg is query)
    float v[5][4];
    #pragma unroll
    for (int kt = 0; kt < 5; kt++) {
        int kk = kt * 16 + lm;
        int g  = q0 - 64 + w * 16 + kk;
        #pragma unroll
        for (int reg = 0; reg < 4; reg++) {
            int r = g16 * 4 + reg;
            bool valid = (kk >= r) && (kk <= r + 64) && (g >= 0);
            v[kt][reg] = valid
                ? sc[kt][reg] * 0.125f + 0.1f * __expf(-0.1f * (float)(64 + r - kk))
                : NEGV;
        }
    }

    // ---- in-register softmax: per-row (reg) reduce over 16-lane col groups
    float mx[4], sm[4];
    #pragma unroll
    for (int reg = 0; reg < 4; reg++) {
        float m = v[0][reg];
        #pragma unroll
        for (int kt = 1; kt < 5; kt++) m = fmaxf(m, v[kt][reg]);
        mx[reg] = m;
    }
    #pragma unroll
    for (int off = 1; off < 16; off <<= 1)
        #pragma unroll
        for (int reg = 0; reg < 4; reg++)
            mx[reg] = fmaxf(mx[reg], __shfl_xor(mx[reg], off));
    float p[5][4];
    #pragma unroll
    for (int reg = 0; reg < 4; reg++) {
        float s = 0.f;
        #pragma unroll
        for (int kt = 0; kt < 5; kt++) {
            float e = __expf(v[kt][reg] - mx[reg]);
            p[kt][reg] = e;
            s += e;
        }
        sm[reg] = s;
    }
    #pragma unroll
    for (int off = 1; off < 16; off <<= 1)
        #pragma unroll
        for (int reg = 0; reg < 4; reg++)
            sm[reg] += __shfl_xor(sm[reg], off);
    #pragma unroll
    for (int reg = 0; reg < 4; reg++) {
        float inv = 1.f / sm[reg];
        #pragma unroll
        for (int kt = 0; kt < 5; kt++) p[kt][reg] *= inv;
    }

    // ---- P -> LDS (bf16), zero-pad kk in [80,96)
    #pragma unroll
    for (int kt = 0; kt < 5; kt++)
        #pragma unroll
        for (int reg = 0; reg < 4; reg++)
            Ps[w][g16 * 4 + reg][kt * 16 + lm] = f2bf(p[kt][reg]);
    #pragma unroll
    for (int reg = 0; reg < 4; reg++)
        Ps[w][g16 * 4 + reg][80 + lm] = 0;

    // ---- PV: 3 k-steps x 4 d-tiles (same-wave LDS RAW, no barrier needed)
    float4v oacc[4] = {};
    #pragma unroll
    for (int ks = 0; ks < 3; ks++) {
        short8 pa = *(const short8*)&Ps[w][lm][ks * 32 + lk8];
        #pragma unroll
        for (int nt = 0; nt < 4; nt++) {
            short8 vb = *(const short8*)&Vt[(nt * 16 + lm) * 136 + w * 16 + ks * 32 + lk8];
            oacc[nt] = __builtin_amdgcn_mfma_f32_16x16x32_bf16(pa, vb, oacc[nt], 0, 0, 0);
        }
    }

    // ---- ctx write (bf16): col=lm is d, rows g16*4+reg are queries
    #pragma unroll
    for (int nt = 0; nt < 4; nt++)
        #pragma unroll
        for (int reg = 0; reg < 4; reg++) {
            int i = q0 + w * 16 + g16 * 4 + reg;
            ctxb[(size_t)i * 512 + h * 64 + nt * 16 + lm] = f2bf(oacc[nt][reg]);
        }

    __syncthreads();

    // ---- attn_w: only q0==0 (left edge) and q0==1984 (right edge) nonzero
    for (int t = tid; t < 64 * 128; t += 256) {
        int ql = t >> 7, slot = t & 127;
        int i  = q0 + ql;
        float val = 0.f;
        if (q0 == 0) {
            if (slot <= ql) {
                int kk = (ql & 15) + slot + 64 - ql;
                val = bf2f(Ps[ql >> 4][ql & 15][kk]);
            }
        } else if (q0 == SEQ - 64) {
            if (slot <= 64) {
                int kk = (ql & 15) + slot;
                val = bf2f(Ps[ql >> 4][ql & 15][kk]);
            }
        }
        attnw[((size_t)h * SEQ + i) * 2 * WIN + slot] = val;
    }
}

// ---------------------------------------------------------------------------
extern "C" void kernel_launch(void* const* d_in, const int* in_sizes, int n_in,
                              void* d_out, int out_size, void* d_ws, size_t ws_size,
                              hipStream_t stream)
{
    const float* query = (const float*)d_in[0];
    const float* key   = (const float*)d_in[1];
    const float* value = (const float*)d_in[2];
    const float* Wq    = (const float*)d_in[3];
    const float* Wk    = (const float*)d_in[4];
    const float* Wv    = (const float*)d_in[5];
    const float* Wo    = (const float*)d_in[6];
    const float* bo    = (const float*)d_in[7];

    float* out   = (float*)d_out;                 // 2048*512 f32
    float* attnw = out + SEQ * DM;                // 8*2048*128 f32

    unsigned short* qb   = (unsigned short*)d_ws;       // casts of inputs
    unsigned short* kb   = qb  + 1048576;
    unsigned short* vb   = kb  + 1048576;
    unsigned short* wqb  = vb  + 1048576;
    unsigned short* wkb  = wqb + 262144;
    unsigned short* wvb  = wkb + 262144;
    unsigned short* wob  = wvb + 262144;
    unsigned short* Qp   = wob + 262144;                // projected, bf16
    unsigned short* Kp   = Qp  + 1048576;
    unsigned short* Vp   = Kp  + 1048576;
    unsigned short* ctxb = Vp  + 1048576;

    cast7_kernel<<<2048, 256, 0, stream>>>(query, key, value, Wq, Wk, Wv, Wo, qb);

    dim3 g1(SEQ / 128, DM / 128, 3);
    qkv_gemm_kernel<<<g1, 256, 0, stream>>>(qb, kb, vb, wqb, wkb, wvb, Qp, Kp, Vp);

    dim3 g2(SEQ / 64, NHEAD);
    attn_kernel<<<g2, 256, 0, stream>>>(Qp, Kp, Vp, ctxb, attnw);

    dim3 g3(SEQ / 128, DM / 128);
    out_gemm_kernel<<<g3, 256, 0, stream>>>(ctxb, wob, bo, out);
}

// Round 6
// 111.858 us; speedup vs baseline: 1.5260x; 1.0170x over previous
//
#include <hip/hip_runtime.h>
#include <stdint.h>

#define SEQ   2048
#define DM    512
#define NHEAD 8
#define DKH   64
#define WIN   64
#define NEGV  -1000000000.0f

typedef __attribute__((ext_vector_type(8))) short          short8;
typedef __attribute__((ext_vector_type(4))) float          float4v;
typedef __attribute__((ext_vector_type(8))) unsigned short ushort8v;

__device__ __forceinline__ unsigned short f2bf(float x) {
    uint32_t u = __float_as_uint(x);
    uint32_t r = (u + 0x7FFFu + ((u >> 16) & 1u)) >> 16;
    return (unsigned short)r;
}
__device__ __forceinline__ float bf2f(unsigned short u) {
    return __uint_as_float(((uint32_t)u) << 16);
}

// async 16B global -> LDS (wave-uniform base + lane*16 pattern)
__device__ __forceinline__ void async_cp16(const void* g, void* lds) {
    __builtin_amdgcn_global_load_lds(
        (const __attribute__((address_space(1))) unsigned int*)(uintptr_t)g,
        (__attribute__((address_space(3))) unsigned int*)(uint32_t)(uintptr_t)lds,
        16, 0, 0);
}

// ---------------------------------------------------------------------------
// Fused f32 -> bf16 cast of q,k,v (1M each) + Wq,Wk,Wv,Wo (256K each).
// ---------------------------------------------------------------------------
__global__ __launch_bounds__(256)
void cast7_kernel(const float* __restrict__ q, const float* __restrict__ k,
                  const float* __restrict__ v, const float* __restrict__ wq,
                  const float* __restrict__ wk, const float* __restrict__ wv,
                  const float* __restrict__ wo, unsigned short* __restrict__ dst)
{
    int g = (blockIdx.x * 256 + threadIdx.x) * 8;   // < 4194304
    const float* src; int off;
    if      (g < 1048576) { src = q;  off = g; }
    else if (g < 2097152) { src = k;  off = g - 1048576; }
    else if (g < 3145728) { src = v;  off = g - 2097152; }
    else if (g < 3407872) { src = wq; off = g - 3145728; }
    else if (g < 3670016) { src = wk; off = g - 3407872; }
    else if (g < 3932160) { src = wv; off = g - 3670016; }
    else                  { src = wo; off = g - 3932160; }
    float4 x0 = *(const float4*)(src + off);
    float4 x1 = *(const float4*)(src + off + 4);
    ushort8v o;
    o[0] = f2bf(x0.x); o[1] = f2bf(x0.y); o[2] = f2bf(x0.z); o[3] = f2bf(x0.w);
    o[4] = f2bf(x1.x); o[5] = f2bf(x1.y); o[6] = f2bf(x1.z); o[7] = f2bf(x1.w);
    *(ushort8v*)(dst + g) = o;
}

// ---------------------------------------------------------------------------
// bf16 MFMA NT GEMM: C[m,n] = sum_k A[m,k]*B[n,k] (+bias[n]).
// OUT_BF16 selects bf16 or f32 output. 128x128 tile, 256 thr = 4 waves.
// ---------------------------------------------------------------------------
template<bool BIAS, bool OUT_BF16>
__device__ __forceinline__ void gemm_mfma_body(const unsigned short* __restrict__ A,
                                               const unsigned short* __restrict__ B,
                                               const float* __restrict__ bias,
                                               void* __restrict__ Cv)
{
    __shared__ __align__(16) unsigned short As[128 * 32];
    __shared__ __align__(16) unsigned short Bs[128 * 32];

    const int tid  = threadIdx.x;
    const int m0   = blockIdx.x * 128;
    const int n0   = blockIdx.y * 128;
    const int lane = tid & 63;
    const int wave = tid >> 6;
    const int wm   = (wave >> 1) * 64;
    const int wn   = (wave & 1) * 64;
    const int lm   = lane & 15;
    const int lk   = (lane >> 4) * 8;

    float4v acc[4][4] = {};

    for (int k0 = 0; k0 < 512; k0 += 32) {
        #pragma unroll
        for (int h = 0; h < 2; h++) {
            int c  = tid + h * 256;
            int r  = c >> 2;
            int kc = (c & 3) * 8;
            async_cp16(A + (size_t)(m0 + r) * 512 + k0 + kc, As + c * 8);
            async_cp16(B + (size_t)(n0 + r) * 512 + k0 + kc, Bs + c * 8);
        }
        __syncthreads();

        short8 av[4], bv[4];
        #pragma unroll
        for (int mt = 0; mt < 4; mt++)
            av[mt] = *(const short8*)(As + (wm + mt * 16 + lm) * 32 + lk);
        #pragma unroll
        for (int nt = 0; nt < 4; nt++)
            bv[nt] = *(const short8*)(Bs + (wn + nt * 16 + lm) * 32 + lk);
        #pragma unroll
        for (int mt = 0; mt < 4; mt++)
            #pragma unroll
            for (int nt = 0; nt < 4; nt++)
                acc[mt][nt] = __builtin_amdgcn_mfma_f32_16x16x32_bf16(
                    av[mt], bv[nt], acc[mt][nt], 0, 0, 0);
        __syncthreads();
    }

    const int r0 = (lane >> 4) * 4;
    const int cn = lane & 15;
    #pragma unroll
    for (int nt = 0; nt < 4; nt++) {
        int gcol = n0 + wn + nt * 16 + cn;
        float b = BIAS ? bias[gcol] : 0.f;
        #pragma unroll
        for (int mt = 0; mt < 4; mt++) {
            int grow = m0 + wm + mt * 16 + r0;
            #pragma unroll
            for (int reg = 0; reg < 4; reg++) {
                float val = acc[mt][nt][reg] + b;
                if (OUT_BF16)
                    ((unsigned short*)Cv)[(size_t)(grow + reg) * 512 + gcol] = f2bf(val);
                else
                    ((float*)Cv)[(size_t)(grow + reg) * 512 + gcol] = val;
            }
        }
    }
}

__global__ __launch_bounds__(256)
void qkv_gemm_kernel(const unsigned short* __restrict__ qb,
                     const unsigned short* __restrict__ kb,
                     const unsigned short* __restrict__ vb,
                     const unsigned short* __restrict__ wqb,
                     const unsigned short* __restrict__ wkb,
                     const unsigned short* __restrict__ wvb,
                     unsigned short* __restrict__ Qp, unsigned short* __restrict__ Kp,
                     unsigned short* __restrict__ Vp)
{
    const unsigned short *A, *B; unsigned short* C;
    if (blockIdx.z == 0)      { A = qb; B = wqb; C = Qp; }
    else if (blockIdx.z == 1) { A = kb; B = wkb; C = Kp; }
    else                      { A = vb; B = wvb; C = Vp; }
    gemm_mfma_body<false, true>(A, B, nullptr, C);
}

__global__ __launch_bounds__(256)
void out_gemm_kernel(const unsigned short* __restrict__ ctxb,
                     const unsigned short* __restrict__ wob,
                     const float* __restrict__ bo, float* __restrict__ out)
{
    gemm_mfma_body<true, false>(ctxb, wob, bo, out);
}

// ---------------------------------------------------------------------------
// MFMA windowed attention. Block = 64 queries x 1 head, 256 thr = 4 waves.
// Wave w owns queries q0+w*16..+15 and local key rows w*16..w*16+79.
// Vt stride = 152 ushorts (304B = 19x16B aligned; 2-way bank alias = free).
// Keys 128..151 explicitly zeroed: wave 3's PV reads reach key 143 with
// zero P operands — uninit LDS there was the r4/r5 NaN source (0*NaN=NaN).
// ---------------------------------------------------------------------------
#define VTS 152

__global__ __launch_bounds__(256)
void attn_kernel(const unsigned short* __restrict__ Qp,
                 const unsigned short* __restrict__ Kp,
                 const unsigned short* __restrict__ Vp,
                 unsigned short* __restrict__ ctxb,
                 float* __restrict__ attnw)
{
    __shared__ __align__(16) unsigned short Qs[64 * 72];    // [q_local][64 k]
    __shared__ __align__(16) unsigned short Ks[128 * 72];   // [key_local][64 k]
    __shared__ __align__(16) unsigned short Vt[64 * VTS];   // [d][key_local 0..151]
    __shared__ __align__(16) unsigned short Ps[4][16][96];  // [wave][q][kk]

    const int h   = blockIdx.y;
    const int q0  = blockIdx.x * 64;
    const int tid = threadIdx.x;

    for (int c = tid; c < 512; c += 256) {
        int row = c >> 3, ch = c & 7;
        *(ushort8v*)&Qs[row * 72 + ch * 8] =
            *(const ushort8v*)&Qp[(size_t)(q0 + row) * 512 + h * 64 + ch * 8];
    }
    for (int c = tid; c < 1024; c += 256) {
        int row = c >> 3, ch = c & 7;
        int g = q0 - 64 + row;
        ushort8v val = {0, 0, 0, 0, 0, 0, 0, 0};
        if (g >= 0)
            val = *(const ushort8v*)&Kp[(size_t)g * 512 + h * 64 + ch * 8];
        *(ushort8v*)&Ks[row * 72 + ch * 8] = val;
    }
    {
        int key = tid >> 1, dh = tid & 1;
        int g = q0 - 64 + key;
        ushort8v vv[4];
        #pragma unroll
        for (int j = 0; j < 4; j++) {
            ushort8v z = {0, 0, 0, 0, 0, 0, 0, 0};
            vv[j] = (g >= 0)
                ? *(const ushort8v*)&Vp[(size_t)g * 512 + h * 64 + dh * 32 + j * 8]
                : z;
        }
        #pragma unroll
        for (int j = 0; j < 4; j++)
            #pragma unroll
            for (int e = 0; e < 8; e++)
                Vt[(dh * 32 + j * 8 + e) * VTS + key] = vv[j][e];
    }
    // zero pad keys 128..151 for all 64 d-rows (deterministic 0*0 tail)
    for (int t = tid; t < 64 * 24; t += 256) {
        int d = t / 24, c = 128 + (t % 24);
        Vt[d * VTS + c] = 0;
    }
    __syncthreads();

    const int lane = tid & 63;
    const int w    = tid >> 6;
    const int lm   = lane & 15;
    const int g16  = lane >> 4;
    const int lk8  = g16 * 8;

    short8 av0 = *(const short8*)&Qs[(w * 16 + lm) * 72 + lk8];
    short8 av1 = *(const short8*)&Qs[(w * 16 + lm) * 72 + 32 + lk8];
    float4v sc[5];
    #pragma unroll
    for (int kt = 0; kt < 5; kt++) {
        const unsigned short* kr = &Ks[(w * 16 + kt * 16 + lm) * 72];
        short8 b0 = *(const short8*)(kr + lk8);
        short8 b1 = *(const short8*)(kr + 32 + lk8);
        float4v a = {0.f, 0.f, 0.f, 0.f};
        a = __builtin_amdgcn_mfma_f32_16x16x32_bf16(av0, b0, a, 0, 0, 0);
        a = __builtin_amdgcn_mfma_f32_16x16x32_bf16(av1, b1, a, 0, 0, 0);
        sc[kt] = a;
    }

    float v[5][4];
    #pragma unroll
    for (int kt = 0; kt < 5; kt++) {
        int kk = kt * 16 + lm;
        int g  = q0 - 64 + w * 16 + kk;
        #pragma unroll
        for (int reg = 0; reg < 4; reg++) {
            int rr = g16 * 4 + reg;
            bool valid = (kk >= rr) && (kk <= rr + 64) && (g >= 0);
            v[kt][reg] = valid
                ? sc[kt][reg] * 0.125f + 0.1f * __expf(-0.1f * (float)(64 + rr - kk))
                : NEGV;
        }
    }

    float mx[4], sm[4];
    #pragma unroll
    for (int reg = 0; reg < 4; reg++) {
        float m = v[0][reg];
        #pragma unroll
        for (int kt = 1; kt < 5; kt++) m = fmaxf(m, v[kt][reg]);
        mx[reg] = m;
    }
    #pragma unroll
    for (int off = 1; off < 16; off <<= 1)
        #pragma unroll
        for (int reg = 0; reg < 4; reg++)
            mx[reg] = fmaxf(mx[reg], __shfl_xor(mx[reg], off));
    float p[5][4];
    #pragma unroll
    for (int reg = 0; reg < 4; reg++) {
        float s = 0.f;
        #pragma unroll
        for (int kt = 0; kt < 5; kt++) {
            float e = __expf(v[kt][reg] - mx[reg]);
            p[kt][reg] = e;
            s += e;
        }
        sm[reg] = s;
    }
    #pragma unroll
    for (int off = 1; off < 16; off <<= 1)
        #pragma unroll
        for (int reg = 0; reg < 4; reg++)
            sm[reg] += __shfl_xor(sm[reg], off);
    #pragma unroll
    for (int reg = 0; reg < 4; reg++) {
        float inv = 1.f / sm[reg];
        #pragma unroll
        for (int kt = 0; kt < 5; kt++) p[kt][reg] *= inv;
    }

    #pragma unroll
    for (int kt = 0; kt < 5; kt++)
        #pragma unroll
        for (int reg = 0; reg < 4; reg++)
            Ps[w][g16 * 4 + reg][kt * 16 + lm] = f2bf(p[kt][reg]);
    #pragma unroll
    for (int reg = 0; reg < 4; reg++)
        Ps[w][g16 * 4 + reg][80 + lm] = 0;

    // Cross-lane LDS RAW: Ps written by rows g16*4+reg, read below by rows lm.
    __syncthreads();

    float4v oacc[4] = {};
    #pragma unroll
    for (int ks = 0; ks < 3; ks++) {
        short8 pa = *(const short8*)&Ps[w][lm][ks * 32 + lk8];
        #pragma unroll
        for (int nt = 0; nt < 4; nt++) {
            short8 vb = *(const short8*)&Vt[(nt * 16 + lm) * VTS + w * 16 + ks * 32 + lk8];
            oacc[nt] = __builtin_amdgcn_mfma_f32_16x16x32_bf16(pa, vb, oacc[nt], 0, 0, 0);
        }
    }

    #pragma unroll
    for (int nt = 0; nt < 4; nt++)
        #pragma unroll
        for (int reg = 0; reg < 4; reg++) {
            int i = q0 + w * 16 + g16 * 4 + reg;
            ctxb[(size_t)i * 512 + h * 64 + nt * 16 + lm] = f2bf(oacc[nt][reg]);
        }

    __syncthreads();

    for (int t = tid; t < 64 * 128; t += 256) {
        int ql = t >> 7, slot = t & 127;
        int i  = q0 + ql;
        float val = 0.f;
        if (q0 == 0) {
            if (slot <= ql) {
                int kk = (ql & 15) + slot + 64 - ql;
                val = bf2f(Ps[ql >> 4][ql & 15][kk]);
            }
        } else if (q0 == SEQ - 64) {
            if (slot <= 64) {
                int kk = (ql & 15) + slot;
                val = bf2f(Ps[ql >> 4][ql & 15][kk]);
            }
        }
        attnw[((size_t)h * SEQ + i) * 2 * WIN + slot] = val;
    }
}

// ---------------------------------------------------------------------------
extern "C" void kernel_launch(void* const* d_in, const int* in_sizes, int n_in,
                              void* d_out, int out_size, void* d_ws, size_t ws_size,
                              hipStream_t stream)
{
    const float* query = (const float*)d_in[0];
    const float* key   = (const float*)d_in[1];
    const float* value = (const float*)d_in[2];
    const float* Wq    = (const float*)d_in[3];
    const float* Wk    = (const float*)d_in[4];
    const float* Wv    = (const float*)d_in[5];
    const float* Wo    = (const float*)d_in[6];
    const float* bo    = (const float*)d_in[7];

    float* out   = (float*)d_out;                 // 2048*512 f32
    float* attnw = out + SEQ * DM;                // 8*2048*128 f32

    unsigned short* qb   = (unsigned short*)d_ws;       // casts of inputs
    unsigned short* kb   = qb  + 1048576;
    unsigned short* vb   = kb  + 1048576;
    unsigned short* wqb  = vb  + 1048576;
    unsigned short* wkb  = wqb + 262144;
    unsigned short* wvb  = wkb + 262144;
    unsigned short* wob  = wvb + 262144;
    unsigned short* Qp   = wob + 262144;                // projected, bf16
    unsigned short* Kp   = Qp  + 1048576;
    unsigned short* Vp   = Kp  + 1048576;
    unsigned short* ctxb = Vp  + 1048576;

    cast7_kernel<<<2048, 256, 0, stream>>>(query, key, value, Wq, Wk, Wv, Wo, qb);

    dim3 g1(SEQ / 128, DM / 128, 3);
    qkv_gemm_kernel<<<g1, 256, 0, stream>>>(qb, kb, vb, wqb, wkb, wvb, Qp, Kp, Vp);

    dim3 g2(SEQ / 64, NHEAD);
    attn_kernel<<<g2, 256, 0, stream>>>(Qp, Kp, Vp, ctxb, attnw);

    dim3 g3(SEQ / 128, DM / 128);
    out_gemm_kernel<<<g3, 256, 0, stream>>>(ctxb, wob, bo, out);
}